// Round 6
// baseline (310.127 us; speedup 1.0000x reference)
//
#include <hip/hip_runtime.h>

#define HH_OFF 229376
#define LQE_OFF 1277952
#define QF_OFF 1507328

#define WS_HE 0
#define WS_HA 33280
#define WS_ATT 66560
#define WS_BATT 70656
#define WS_BH 70720
#define WS_BC 70784
#define WS_LQ 70800
#define WS_G1 70912
#define WS_G2 95488
#define WS_E1 120064
#define WS_E2 128256
#define WS_F1 136448
#define WS_END 140544

#define SSTR 640  // A: 4*4*640*4 = 40960 B -> exactly 4 blocks/CU, grid 1024 = 1 round
#define BSTR 384  // B: 4*4*384*4 = 24576 B

struct Params {
  const float *own, *ef, *af, *hid;
  const int *aid, *lid;
  const float *fc1oW, *fc1ob, *aemb, *actemb;
  const float *heW1, *heb1, *heW2, *heb2;
  const float *haW1, *hab1, *haW2, *hab2;
  const float *mi, *mo;
  const float *gWih, *gWhh, *gbih, *gbhh;
  const float *fc2nW, *fc2nb;
  const float *fc1bW, *fc1bb;
  const float *g2Wih, *g2Whh, *g2bih, *g2bhh;
  const float *eW1, *eb1, *eW2, *eb2;
  const float *fc3W, *fc3b;
  const float *mlpW, *mlpb;
};

__device__ __forceinline__ float sigm(float x) {
  x = fminf(fmaxf(x, -30.f), 30.f);
  return 1.f / (1.f + __expf(-x));
}
__device__ __forceinline__ float tanh_(float x) {
  x = fminf(fmaxf(x, -15.f), 15.f);
  float e = __expf(-2.f * x);
  return (1.f - e) / (1.f + e);
}

// ---------------------------------------------------------------------------
// prep: fold merger softmax into hypernet weights; transpose-pack all dense
// weights into float4-friendly layouts; block 0 computes g[0:8] -> local_q.
// ---------------------------------------------------------------------------
__global__ void __launch_bounds__(512) prep_kernel(Params p, float* __restrict__ ws) {
  const int tid = threadIdx.x;
  if (blockIdx.x == 0) {
    __shared__ float g8[8][64];
    __shared__ float x2s[8][64];
    const int w = __builtin_amdgcn_readfirstlane(tid >> 6);
    const int lane = tid & 63;
    {
      float acc = p.fc1bb[lane];
      const float* ow = p.own + w * 30;
      for (int d = 0; d < 30; ++d) acc += ow[d] * p.fc1bW[d * 64 + lane];
      x2s[w][lane] = fmaxf(acc, 0.f);
      float a0 = p.g2bih[lane], a1 = p.g2bih[64 + lane], a2 = p.g2bih[128 + lane];
      float b0 = p.g2bhh[lane], b1 = p.g2bhh[64 + lane], b2 = p.g2bhh[128 + lane];
      const float* hidw = p.hid + w * 64;
      for (int k = 0; k < 64; ++k) {
        float xk = x2s[w][k];
        float hk = hidw[k];
        a0 += xk * p.g2Wih[k * 192 + lane];
        a1 += xk * p.g2Wih[k * 192 + 64 + lane];
        a2 += xk * p.g2Wih[k * 192 + 128 + lane];
        b0 += hk * p.g2Whh[k * 192 + lane];
        b1 += hk * p.g2Whh[k * 192 + 64 + lane];
        b2 += hk * p.g2Whh[k * 192 + 128 + lane];
      }
      float r = sigm(a0 + b0), z = sigm(a1 + b1);
      float n = tanh_(a2 + r * b2);
      g8[w][lane] = (1.f - z) * n + z * hidw[lane];
    }
    __syncthreads();
    if (tid < 112) {
      int a = tid / 14, c = tid % 14;
      float lacc = p.mlpb[a * 14 + c];
      for (int h = 0; h < 64; ++h) lacc += g8[a][h] * p.mlpW[(a * 64 + h) * 14 + c];
      ws[WS_LQ + tid] = lacc;
    }
    return;
  }
  const int idx = (int)(blockIdx.x - 1) * 512 + tid;
  if (idx >= WS_END) return;
  const float mo0 = sigm(p.mo[0] - p.mo[1]);
  const float mo1 = 1.f - mo0;
  if (idx < 33280) {
    int c = idx >> 8, rem = idx & 255, h = rem >> 2, q = rem & 3;
    int t = c * 4 + q;
    float mw0 = sigm(p.mi[h] - p.mi[64 + h]);
    float mw1 = 1.f - mw0;
    float v;
    if (t < 512) {
      int d = t >> 6, j = t & 63;
      v = mw0 * p.heW2[j * 1154 + d * 128 + h] + mw1 * p.heW2[j * 1154 + d * 128 + 64 + h];
    } else {
      int d = t - 512;
      v = mw0 * p.heb2[d * 128 + h] + mw1 * p.heb2[d * 128 + 64 + h];
    }
    ws[WS_HE + idx] = v;
  } else if (idx < 66560) {
    int rel = idx - 33280;
    int c = rel >> 8, rem = rel & 255, h = rem >> 2, q = rem & 3;
    int t = c * 4 + q;
    float mw0 = sigm(p.mi[h] - p.mi[64 + h]);
    float mw1 = 1.f - mw0;
    float v;
    if (t < 512) {
      int d = t >> 6, j = t & 63;
      v = mw0 * p.haW2[j * 1024 + d * 128 + h] + mw1 * p.haW2[j * 1024 + d * 128 + 64 + h];
    } else {
      int d = t - 512;
      v = mw0 * p.hab2[d * 128 + h] + mw1 * p.hab2[d * 128 + 64 + h];
    }
    ws[WS_HA + rel] = v;
  } else if (idx < 70656) {
    int rel = idx - 66560;
    int c = rel >> 8, rem = rel & 255, j = rem >> 2, q = rem & 3;
    int h = c * 4 + q;
    ws[WS_ATT + rel] = mo0 * p.heW2[j * 1154 + 1024 + 2 * h] +
                       mo1 * p.heW2[j * 1154 + 1024 + 2 * h + 1];
  } else if (idx < 70720) {
    int j = idx - 70656;
    ws[WS_BATT + j] = mo0 * p.heW2[j * 1154 + 1152] + mo1 * p.heW2[j * 1154 + 1153];
  } else if (idx < 70784) {
    int h = idx - 70720;
    ws[WS_BH + h] = mo0 * p.heb2[1024 + 2 * h] + mo1 * p.heb2[1024 + 2 * h + 1];
  } else if (idx == 70784) {
    ws[WS_BC] = mo0 * p.heb2[1152] + mo1 * p.heb2[1153];
  } else if (idx < WS_G1) {
    return;  // LQ region handled by block 0
  } else if (idx < WS_G2) {
    int rel = idx - WS_G1;
    int k4 = rel / 1536, r2 = rel % 1536;
    int j = r2 >> 8, lane = (r2 & 255) >> 2, q = rel & 3;
    int row = 4 * k4 + q;
    ws[idx] = (j < 3) ? p.gWih[row * 192 + j * 64 + lane]
                      : p.gWhh[row * 192 + (j - 3) * 64 + lane];
  } else if (idx < WS_E1) {
    int rel = idx - WS_G2;
    int k4 = rel / 1536, r2 = rel % 1536;
    int j = r2 >> 8, lane = (r2 & 255) >> 2, q = rel & 3;
    int row = 4 * k4 + q;
    ws[idx] = (j < 3) ? p.g2Wih[row * 192 + j * 64 + lane]
                      : p.g2Whh[row * 192 + (j - 3) * 64 + lane];
  } else if (idx < WS_E2) {
    int rel = idx - WS_E1;
    int k4 = rel >> 9, j = (rel >> 8) & 1, lane = (rel & 255) >> 2, q = rel & 3;
    int row = 4 * k4 + q;
    ws[idx] = p.eW1[row * 128 + j * 64 + lane];
  } else if (idx < WS_F1) {
    int rel = idx - WS_E2;
    int k4 = rel >> 8, lane = (rel & 255) >> 2, q = rel & 3;
    int row = 4 * k4 + q;
    ws[idx] = p.eW2[row * 64 + lane];
  } else {
    int rel = idx - WS_F1;
    int k4 = rel >> 9, j = (rel >> 8) & 1, lane = (rel & 255) >> 2, q = rel & 3;
    int row = 4 * k4 + q;
    float v;
    if (row < 30) v = (j == 0) ? p.fc1oW[row * 64 + lane] : p.fc1bW[row * 64 + lane];
    else if (row == 30) v = (j == 0) ? p.fc1ob[lane] : p.fc1bb[lane];
    else v = 0.f;
    ws[idx] = v;
  }
}

// ---------------------------------------------------------------------------
// kernel A: hypernet + fc1_own + GRU1 + attack + q_normal.
// LDS exactly 40960 B/block -> 4 blocks/CU; grid 1024 = 256 CU x 4 = one
// residency round, no tail (round-5: 41472 B -> 3/CU -> 2 rounds, Occ 20%).
// Epilogue reordered (attack BEFORE q_normal) to kill the qn live range that
// was spilling ~40 MB/dispatch.
// ---------------------------------------------------------------------------
__global__ void __launch_bounds__(256, 2) kernelA(Params p, const float* __restrict__ ws,
                                                  float* __restrict__ out) {
  __shared__ float smem[4 * 4 * SSTR];
  const int w = __builtin_amdgcn_readfirstlane((int)(threadIdx.x >> 6));
  const int lane = threadIdx.x & 63;
  float* S = &smem[w * 4 * SSTR];
  const int i0 = blockIdx.x * 16 + w * 4;

  // ---- stage ef, af
#pragma unroll
  for (int s = 0; s < 4; ++s) {
    S[s * SSTR + 520 + lane] = p.ef[(i0 + s) * 64 + lane];
    if (lane < 56) S[s * SSTR + 584 + lane] = p.af[(i0 + s) * 56 + lane];
  }
  float macc[4] = {0.f, 0.f, 0.f, 0.f};
  // ---- enemy T build
  {
    float w1[8];
#pragma unroll
    for (int d = 0; d < 8; ++d) w1[d] = p.heW1[d * 64 + lane];
    const float b1 = p.heb1[lane];
#pragma unroll
    for (int s = 0; s < 4; ++s) {
      float T[8], fs[8];
#pragma unroll
      for (int d = 0; d < 8; ++d) { T[d] = 0.f; fs[d] = 0.f; }
#pragma unroll
      for (int e = 0; e < 8; ++e) {
        float4 a = *(const float4*)&S[s * SSTR + 520 + e * 8];
        float4 b = *(const float4*)&S[s * SSTR + 520 + e * 8 + 4];
        float acc = b1 + a.x * w1[0] + a.y * w1[1] + a.z * w1[2] + a.w * w1[3] +
                    b.x * w1[4] + b.y * w1[5] + b.z * w1[6] + b.w * w1[7];
        float r = fmaxf(acc, 0.f);
        T[0] += r * a.x; T[1] += r * a.y; T[2] += r * a.z; T[3] += r * a.w;
        T[4] += r * b.x; T[5] += r * b.y; T[6] += r * b.z; T[7] += r * b.w;
        fs[0] += a.x; fs[1] += a.y; fs[2] += a.z; fs[3] += a.w;
        fs[4] += b.x; fs[5] += b.y; fs[6] += b.z; fs[7] += b.w;
      }
#pragma unroll
      for (int d = 0; d < 8; ++d) S[s * SSTR + d * 64 + lane] = T[d];
      if (lane == 0) {
#pragma unroll
        for (int d = 0; d < 8; ++d) S[s * SSTR + 512 + d] = fs[d];
      }
    }
  }
  // ---- HE contraction
  {
    const float4* W4 = (const float4*)(ws + WS_HE);
    for (int c = 0; c < 130; ++c) {
      float4 wv = W4[c * 64 + lane];
#pragma unroll
      for (int s = 0; s < 4; ++s) {
        float4 tv = *(const float4*)&S[s * SSTR + c * 4];
        macc[s] += tv.x * wv.x + tv.y * wv.y + tv.z * wv.z + tv.w * wv.w;
      }
    }
  }
  // ---- ally T build
  {
    float w1[8];
#pragma unroll
    for (int d = 0; d < 8; ++d) w1[d] = p.haW1[d * 64 + lane];
    const float b1 = p.hab1[lane];
#pragma unroll
    for (int s = 0; s < 4; ++s) {
      float T[8], fs[8];
#pragma unroll
      for (int d = 0; d < 8; ++d) { T[d] = 0.f; fs[d] = 0.f; }
#pragma unroll
      for (int e = 0; e < 7; ++e) {
        float4 a = *(const float4*)&S[s * SSTR + 584 + e * 8];
        float4 b = *(const float4*)&S[s * SSTR + 584 + e * 8 + 4];
        float acc = b1 + a.x * w1[0] + a.y * w1[1] + a.z * w1[2] + a.w * w1[3] +
                    b.x * w1[4] + b.y * w1[5] + b.z * w1[6] + b.w * w1[7];
        float r = fmaxf(acc, 0.f);
        T[0] += r * a.x; T[1] += r * a.y; T[2] += r * a.z; T[3] += r * a.w;
        T[4] += r * b.x; T[5] += r * b.y; T[6] += r * b.z; T[7] += r * b.w;
        fs[0] += a.x; fs[1] += a.y; fs[2] += a.z; fs[3] += a.w;
        fs[4] += b.x; fs[5] += b.y; fs[6] += b.z; fs[7] += b.w;
      }
#pragma unroll
      for (int d = 0; d < 8; ++d) S[s * SSTR + d * 64 + lane] = T[d];
      if (lane == 0) {
#pragma unroll
        for (int d = 0; d < 8; ++d) S[s * SSTR + 512 + d] = fs[d];
      }
    }
  }
  // ---- HA contraction
  {
    const float4* W4 = (const float4*)(ws + WS_HA);
    for (int c = 0; c < 130; ++c) {
      float4 wv = W4[c * 64 + lane];
#pragma unroll
      for (int s = 0; s < 4; ++s) {
        float4 tv = *(const float4*)&S[s * SSTR + c * 4];
        macc[s] += tv.x * wv.x + tv.y * wv.y + tv.z * wv.z + tv.w * wv.w;
      }
    }
  }
  // ---- stage hid and own (T region dead now; own goes over af)
#pragma unroll
  for (int s = 0; s < 4; ++s) {
    S[s * SSTR + 64 + lane] = p.hid[(i0 + s) * 64 + lane];
    if (lane < 32)
      S[s * SSTR + 584 + lane] =
          (lane < 30) ? p.own[(i0 + s) * 30 + lane] : (lane == 30 ? 1.f : 0.f);
  }
  // ---- fc1_own: emb_own (bias folded via own[30]=1) + merged -> x at +0
  {
    float aO[4] = {0.f, 0.f, 0.f, 0.f};
    const float4* F = (const float4*)(ws + WS_F1);
    for (int k4 = 0; k4 < 8; ++k4) {
      float4 wo = F[k4 * 128 + lane];
#pragma unroll
      for (int s = 0; s < 4; ++s) {
        float4 o4 = *(const float4*)&S[s * SSTR + 584 + k4 * 4];
        aO[s] += o4.x * wo.x + o4.y * wo.y + o4.z * wo.z + o4.w * wo.w;
      }
    }
#pragma unroll
    for (int s = 0; s < 4; ++s) {
      const int i = i0 + s;
      float x = aO[s] + p.aemb[p.aid[i] * 64 + lane] + p.actemb[p.lid[i] * 64 + lane] + macc[s];
      S[s * SSTR + lane] = fmaxf(x, 0.f);
    }
  }
  // ---- GRU1 (x at +0, hid at +64) -> hh at +128 and out
  {
    const float bi0 = p.gbih[lane] + p.gbhh[lane];
    const float bi1 = p.gbih[64 + lane] + p.gbhh[64 + lane];
    const float bi2i = p.gbih[128 + lane];
    const float bi2h = p.gbhh[128 + lane];
    float A0[4], A1[4], A2[4], B2[4];
#pragma unroll
    for (int s = 0; s < 4; ++s) { A0[s] = bi0; A1[s] = bi1; A2[s] = bi2i; B2[s] = bi2h; }
    const float4* G = (const float4*)(ws + WS_G1);
    for (int k4 = 0; k4 < 16; ++k4) {
      float4 w0 = G[k4 * 384 + lane];
      float4 w1v = G[k4 * 384 + 64 + lane];
      float4 w2v = G[k4 * 384 + 128 + lane];
      float4 w3 = G[k4 * 384 + 192 + lane];
      float4 w4v = G[k4 * 384 + 256 + lane];
      float4 w5 = G[k4 * 384 + 320 + lane];
#pragma unroll
      for (int s = 0; s < 4; ++s) {
        float4 x4 = *(const float4*)&S[s * SSTR + k4 * 4];
        float4 h4 = *(const float4*)&S[s * SSTR + 64 + k4 * 4];
        A0[s] += x4.x * w0.x + x4.y * w0.y + x4.z * w0.z + x4.w * w0.w +
                 h4.x * w3.x + h4.y * w3.y + h4.z * w3.z + h4.w * w3.w;
        A1[s] += x4.x * w1v.x + x4.y * w1v.y + x4.z * w1v.z + x4.w * w1v.w +
                 h4.x * w4v.x + h4.y * w4v.y + h4.z * w4v.z + h4.w * w4v.w;
        A2[s] += x4.x * w2v.x + x4.y * w2v.y + x4.z * w2v.z + x4.w * w2v.w;
        B2[s] += h4.x * w5.x + h4.y * w5.y + h4.z * w5.z + h4.w * w5.w;
      }
    }
#pragma unroll
    for (int s = 0; s < 4; ++s) {
      float r = sigm(A0[s]);
      float z = sigm(A1[s]);
      float n = tanh_(A2[s] + r * B2[s]);
      float hp = S[s * SSTR + 64 + lane];
      float hh = (1.f - z) * n + z * hp;
      S[s * SSTR + 128 + lane] = hh;
      out[HH_OFF + (i0 + s) * 64 + lane] = hh;
    }
  }
  // ---- attack head (before q_normal: keeps qn live range tiny -> no spill)
  {
    float v4[4];
    const float batt = ws[WS_BATT + lane];
#pragma unroll
    for (int s = 0; s < 4; ++s) v4[s] = batt;
    const float4* A4 = (const float4*)(ws + WS_ATT);
    for (int c = 0; c < 16; ++c) {
      float4 wv = A4[c * 64 + lane];
#pragma unroll
      for (int s = 0; s < 4; ++s) {
        float4 h4 = *(const float4*)&S[s * SSTR + 128 + c * 4];
        v4[s] += h4.x * wv.x + h4.y * wv.y + h4.z * wv.z + h4.w * wv.w;
      }
    }
    float w1[8];
#pragma unroll
    for (int d = 0; d < 8; ++d) w1[d] = p.heW1[d * 64 + lane];
    const float b1 = p.heb1[lane];
    const float bhv = ws[WS_BH + lane];
    const float bc = ws[WS_BC];
#pragma unroll
    for (int s = 0; s < 4; ++s) {
      float red[9];
#pragma unroll
      for (int e = 0; e < 8; ++e) {
        float4 a = *(const float4*)&S[s * SSTR + 520 + e * 8];
        float4 b = *(const float4*)&S[s * SSTR + 520 + e * 8 + 4];
        float acc = b1 + a.x * w1[0] + a.y * w1[1] + a.z * w1[2] + a.w * w1[3] +
                    b.x * w1[4] + b.y * w1[5] + b.z * w1[6] + b.w * w1[7];
        red[e] = fmaxf(acc, 0.f) * v4[s];
      }
      red[8] = S[s * SSTR + 128 + lane] * bhv;
#pragma unroll
      for (int off = 32; off >= 1; off >>= 1) {
#pragma unroll
        for (int t = 0; t < 9; ++t) red[t] += __shfl_xor(red[t], off, 64);
      }
      if (lane == 0) {
#pragma unroll
        for (int e = 0; e < 8; ++e) S[s * SSTR + 448 + 6 + e] = red[e] + red[8] + bc;
      }
    }
  }
  // ---- q_normal + partial assembly: out[q] = qo + lq ; out[LQE] = lq
  if (lane < 56) {
    const int s = lane / 14, c = lane % 14;
    const int i = i0 + s;
    float qo;
    if (c < 6) {
      float acc = p.fc2nb[c];
      for (int h = 0; h < 64; ++h) acc += S[s * SSTR + 128 + h] * p.fc2nW[h * 6 + c];
      qo = acc;
    } else {
      qo = S[s * SSTR + 448 + c];
    }
    float lq = ws[WS_LQ + (i & 7) * 14 + c];
    out[i * 14 + c] = qo + lq;
    out[LQE_OFF + i * 14 + c] = lq;
  }
}

// ---------------------------------------------------------------------------
// kernel B: fc1b + GRU2 + enc + fc3. Writes out[QF], adds qf into out[q].
// Per-sample LDS (BSTR=384): x2@0, hid@64, g@128, own@192(32) then z1@192(128),
// z@320..383.
// ---------------------------------------------------------------------------
__global__ void __launch_bounds__(256, 2) kernelB(Params p, const float* __restrict__ ws,
                                                  float* __restrict__ out) {
  __shared__ float smem[4 * 4 * BSTR];
  const int w = __builtin_amdgcn_readfirstlane((int)(threadIdx.x >> 6));
  const int lane = threadIdx.x & 63;
  float* S = &smem[w * 4 * BSTR];
  const int i0 = blockIdx.x * 16 + w * 4;

  // ---- stage hid, own(+1 pad)
#pragma unroll
  for (int s = 0; s < 4; ++s) {
    S[s * BSTR + 64 + lane] = p.hid[(i0 + s) * 64 + lane];
    if (lane < 32)
      S[s * BSTR + 192 + lane] =
          (lane < 30) ? p.own[(i0 + s) * 30 + lane] : (lane == 30 ? 1.f : 0.f);
  }
  // ---- x2 = relu(own@fc1bW + b) -> +0  (bias folded via own[30]=1)
  {
    float aB[4] = {0.f, 0.f, 0.f, 0.f};
    const float4* F = (const float4*)(ws + WS_F1);
    for (int k4 = 0; k4 < 8; ++k4) {
      float4 wb = F[k4 * 128 + 64 + lane];
#pragma unroll
      for (int s = 0; s < 4; ++s) {
        float4 o4 = *(const float4*)&S[s * BSTR + 192 + k4 * 4];
        aB[s] += o4.x * wb.x + o4.y * wb.y + o4.z * wb.z + o4.w * wb.w;
      }
    }
#pragma unroll
    for (int s = 0; s < 4; ++s) S[s * BSTR + lane] = fmaxf(aB[s], 0.f);
  }
  // ---- GRU2 (x2 at +0, hid at +64) -> g at +128
  {
    const float bi0 = p.g2bih[lane] + p.g2bhh[lane];
    const float bi1 = p.g2bih[64 + lane] + p.g2bhh[64 + lane];
    const float bi2i = p.g2bih[128 + lane];
    const float bi2h = p.g2bhh[128 + lane];
    float A0[4], A1[4], A2[4], B2[4];
#pragma unroll
    for (int s = 0; s < 4; ++s) { A0[s] = bi0; A1[s] = bi1; A2[s] = bi2i; B2[s] = bi2h; }
    const float4* G = (const float4*)(ws + WS_G2);
    for (int k4 = 0; k4 < 16; ++k4) {
      float4 w0 = G[k4 * 384 + lane];
      float4 w1v = G[k4 * 384 + 64 + lane];
      float4 w2v = G[k4 * 384 + 128 + lane];
      float4 w3 = G[k4 * 384 + 192 + lane];
      float4 w4v = G[k4 * 384 + 256 + lane];
      float4 w5 = G[k4 * 384 + 320 + lane];
#pragma unroll
      for (int s = 0; s < 4; ++s) {
        float4 x4 = *(const float4*)&S[s * BSTR + k4 * 4];
        float4 h4 = *(const float4*)&S[s * BSTR + 64 + k4 * 4];
        A0[s] += x4.x * w0.x + x4.y * w0.y + x4.z * w0.z + x4.w * w0.w +
                 h4.x * w3.x + h4.y * w3.y + h4.z * w3.z + h4.w * w3.w;
        A1[s] += x4.x * w1v.x + x4.y * w1v.y + x4.z * w1v.z + x4.w * w1v.w +
                 h4.x * w4v.x + h4.y * w4v.y + h4.z * w4v.z + h4.w * w4v.w;
        A2[s] += x4.x * w2v.x + x4.y * w2v.y + x4.z * w2v.z + x4.w * w2v.w;
        B2[s] += h4.x * w5.x + h4.y * w5.y + h4.z * w5.z + h4.w * w5.w;
      }
    }
#pragma unroll
    for (int s = 0; s < 4; ++s) {
      float r = sigm(A0[s]);
      float z = sigm(A1[s]);
      float n = tanh_(A2[s] + r * B2[s]);
      float hp = S[s * BSTR + 64 + lane];
      S[s * BSTR + 128 + lane] = (1.f - z) * n + z * hp;
    }
  }
  // ---- enc1: z1 = relu(g@W1+b1) -> +192/+256 (own staging dead)
  {
    float C0[4], C1[4];
#pragma unroll
    for (int s = 0; s < 4; ++s) { C0[s] = p.eb1[lane]; C1[s] = p.eb1[64 + lane]; }
    const float4* E1 = (const float4*)(ws + WS_E1);
    for (int k4 = 0; k4 < 16; ++k4) {
      float4 w0 = E1[k4 * 128 + lane];
      float4 w1v = E1[k4 * 128 + 64 + lane];
#pragma unroll
      for (int s = 0; s < 4; ++s) {
        float4 g4 = *(const float4*)&S[s * BSTR + 128 + k4 * 4];
        C0[s] += g4.x * w0.x + g4.y * w0.y + g4.z * w0.z + g4.w * w0.w;
        C1[s] += g4.x * w1v.x + g4.y * w1v.y + g4.z * w1v.z + g4.w * w1v.w;
      }
    }
#pragma unroll
    for (int s = 0; s < 4; ++s) {
      S[s * BSTR + 192 + lane] = fmaxf(C0[s], 0.f);
      S[s * BSTR + 256 + lane] = fmaxf(C1[s], 0.f);
    }
  }
  // ---- enc2: z = z1@W2+b2 -> +320
  {
    float Z[4];
#pragma unroll
    for (int s = 0; s < 4; ++s) Z[s] = p.eb2[lane];
    const float4* E2 = (const float4*)(ws + WS_E2);
    for (int k4 = 0; k4 < 32; ++k4) {
      float4 wv = E2[k4 * 64 + lane];
#pragma unroll
      for (int s = 0; s < 4; ++s) {
        float4 z4 = *(const float4*)&S[s * BSTR + 192 + k4 * 4];
        Z[s] += z4.x * wv.x + z4.y * wv.y + z4.z * wv.z + z4.w * wv.w;
      }
    }
#pragma unroll
    for (int s = 0; s < 4; ++s) S[s * BSTR + 320 + lane] = Z[s];
  }
  // ---- q_f + final add (A already wrote qo + lq)
  if (lane < 56) {
    const int s = lane / 14, c = lane % 14;
    const int i = i0 + s;
    float qf = p.fc3b[c];
    for (int k = 0; k < 64; ++k) qf += S[s * BSTR + 320 + k] * p.fc3W[k * 14 + c];
    out[QF_OFF + i * 14 + c] = qf;
    out[i * 14 + c] += qf;
  }
}

extern "C" void kernel_launch(void* const* d_in, const int* in_sizes, int n_in,
                              void* d_out, int out_size, void* d_ws, size_t ws_size,
                              hipStream_t stream) {
  (void)in_sizes; (void)n_in; (void)out_size; (void)ws_size;
  Params p;
  p.own = (const float*)d_in[1];
  p.ef = (const float*)d_in[2];
  p.af = (const float*)d_in[3];
  p.aid = (const int*)d_in[4];
  p.lid = (const int*)d_in[5];
  p.hid = (const float*)d_in[6];
  p.fc1oW = (const float*)d_in[7];
  p.fc1ob = (const float*)d_in[8];
  p.aemb = (const float*)d_in[9];
  p.actemb = (const float*)d_in[10];
  p.heW1 = (const float*)d_in[11];
  p.heb1 = (const float*)d_in[12];
  p.heW2 = (const float*)d_in[13];
  p.heb2 = (const float*)d_in[14];
  p.haW1 = (const float*)d_in[15];
  p.hab1 = (const float*)d_in[16];
  p.haW2 = (const float*)d_in[17];
  p.hab2 = (const float*)d_in[18];
  p.mi = (const float*)d_in[19];
  p.mo = (const float*)d_in[20];
  p.gWih = (const float*)d_in[21];
  p.gWhh = (const float*)d_in[22];
  p.gbih = (const float*)d_in[23];
  p.gbhh = (const float*)d_in[24];
  p.fc2nW = (const float*)d_in[25];
  p.fc2nb = (const float*)d_in[26];
  p.fc1bW = (const float*)d_in[27];
  p.fc1bb = (const float*)d_in[28];
  p.g2Wih = (const float*)d_in[29];
  p.g2Whh = (const float*)d_in[30];
  p.g2bih = (const float*)d_in[31];
  p.g2bhh = (const float*)d_in[32];
  p.eW1 = (const float*)d_in[33];
  p.eb1 = (const float*)d_in[34];
  p.eW2 = (const float*)d_in[35];
  p.eb2 = (const float*)d_in[36];
  p.fc3W = (const float*)d_in[37];
  p.fc3b = (const float*)d_in[38];
  p.mlpW = (const float*)d_in[39];
  p.mlpb = (const float*)d_in[40];
  float* ws = (float*)d_ws;
  float* out = (float*)d_out;
  prep_kernel<<<dim3(276), dim3(512), 0, stream>>>(p, ws);
  kernelA<<<dim3(1024), dim3(256), 0, stream>>>(p, ws, out);
  kernelB<<<dim3(1024), dim3(256), 0, stream>>>(p, ws, out);
}

// Round 7
// 272.416 us; speedup vs baseline: 1.1384x; 1.1384x over previous
//
#include <hip/hip_runtime.h>

#define HH_OFF 229376
#define LQE_OFF 1277952
#define QF_OFF 1507328

// ws layout (float words)
#define WB_HE 0        // bf16 B-fragments, 17ks*4nc*64lane*8 shorts = 17408 words
#define WB_HA 17408
#define WS_ATT 34816
#define WS_BATT 38912
#define WS_BH 38976
#define WS_BC 39040
#define WS_LQ 39056
#define WS_G1 39168
#define WS_G2 63744
#define WS_E1 88320
#define WS_E2 96512
#define WS_F1 104704
#define WS_END 108800

#define AWAVE 2448  // floats per wave in kernelA LDS (4416B TA + 4*336*4B samples)
#define ASAMP 336   // floats per sample: x@0 hid@64 hh@128 qbuf@192 ef@208 af/own@272
#define TA_SH 552   // shorts per TA row (544 + 8 pad -> conflict-free A-frag reads)
#define BSTR 384

using s8v = __attribute__((ext_vector_type(8))) short;   // 8 bf16 (4 VGPRs)
using f4v = __attribute__((ext_vector_type(4))) float;   // 4 fp32 acc

struct Params {
  const float *own, *ef, *af, *hid;
  const int *aid, *lid;
  const float *fc1oW, *fc1ob, *aemb, *actemb;
  const float *heW1, *heb1, *heW2, *heb2;
  const float *haW1, *hab1, *haW2, *hab2;
  const float *mi, *mo;
  const float *gWih, *gWhh, *gbih, *gbhh;
  const float *fc2nW, *fc2nb;
  const float *fc1bW, *fc1bb;
  const float *g2Wih, *g2Whh, *g2bih, *g2bhh;
  const float *eW1, *eb1, *eW2, *eb2;
  const float *fc3W, *fc3b;
  const float *mlpW, *mlpb;
};

__device__ __forceinline__ float sigm(float x) {
  x = fminf(fmaxf(x, -30.f), 30.f);
  return 1.f / (1.f + __expf(-x));
}
__device__ __forceinline__ float tanh_(float x) {
  x = fminf(fmaxf(x, -15.f), 15.f);
  float e = __expf(-2.f * x);
  return (1.f - e) / (1.f + e);
}
__device__ __forceinline__ unsigned short f2bf(float f) {  // RNE fp32->bf16
  unsigned u = __float_as_uint(f);
  return (unsigned short)((u + 0x7FFFu + ((u >> 16) & 1u)) >> 16);
}

__device__ __forceinline__ float hefold(const Params& p, int t, int h, float mw0, float mw1) {
  if (t < 512) {
    int d = t >> 6, j = t & 63;
    return mw0 * p.heW2[j * 1154 + d * 128 + h] + mw1 * p.heW2[j * 1154 + d * 128 + 64 + h];
  }
  if (t < 520) {
    int d = t - 512;
    return mw0 * p.heb2[d * 128 + h] + mw1 * p.heb2[d * 128 + 64 + h];
  }
  return 0.f;
}
__device__ __forceinline__ float hafold(const Params& p, int t, int h, float mw0, float mw1) {
  if (t < 512) {
    int d = t >> 6, j = t & 63;
    return mw0 * p.haW2[j * 1024 + d * 128 + h] + mw1 * p.haW2[j * 1024 + d * 128 + 64 + h];
  }
  if (t < 520) {
    int d = t - 512;
    return mw0 * p.hab2[d * 128 + h] + mw1 * p.hab2[d * 128 + 64 + h];
  }
  return 0.f;
}

// ---------------------------------------------------------------------------
// prep: pack hypernet weights as bf16 MFMA B-fragments (merger softmax folded);
// pack GRU/enc/fc weights float4-transposed; block 0: g[0:8] -> local_q.
// ---------------------------------------------------------------------------
__global__ void __launch_bounds__(512) prep_kernel(Params p, float* __restrict__ ws) {
  const int tid = threadIdx.x;
  if (blockIdx.x == 0) {
    __shared__ float g8[8][64];
    __shared__ float x2s[8][64];
    const int w = __builtin_amdgcn_readfirstlane(tid >> 6);
    const int lane = tid & 63;
    {
      float acc = p.fc1bb[lane];
      const float* ow = p.own + w * 30;
      for (int d = 0; d < 30; ++d) acc += ow[d] * p.fc1bW[d * 64 + lane];
      x2s[w][lane] = fmaxf(acc, 0.f);
      float a0 = p.g2bih[lane], a1 = p.g2bih[64 + lane], a2 = p.g2bih[128 + lane];
      float b0 = p.g2bhh[lane], b1 = p.g2bhh[64 + lane], b2 = p.g2bhh[128 + lane];
      const float* hidw = p.hid + w * 64;
      for (int k = 0; k < 64; ++k) {
        float xk = x2s[w][k];
        float hk = hidw[k];
        a0 += xk * p.g2Wih[k * 192 + lane];
        a1 += xk * p.g2Wih[k * 192 + 64 + lane];
        a2 += xk * p.g2Wih[k * 192 + 128 + lane];
        b0 += hk * p.g2Whh[k * 192 + lane];
        b1 += hk * p.g2Whh[k * 192 + 64 + lane];
        b2 += hk * p.g2Whh[k * 192 + 128 + lane];
      }
      float r = sigm(a0 + b0), z = sigm(a1 + b1);
      float n = tanh_(a2 + r * b2);
      g8[w][lane] = (1.f - z) * n + z * hidw[lane];
    }
    __syncthreads();
    if (tid < 112) {
      int a = tid / 14, c = tid % 14;
      float lacc = p.mlpb[a * 14 + c];
      for (int h = 0; h < 64; ++h) lacc += g8[a][h] * p.mlpW[(a * 64 + h) * 14 + c];
      ws[WS_LQ + tid] = lacc;
    }
    return;
  }
  const int idx = (int)(blockIdx.x - 1) * 512 + tid;
  if (idx >= WS_END) return;
  const float mo0 = sigm(p.mo[0] - p.mo[1]);
  const float mo1 = 1.f - mo0;
  if (idx < 34816) {
    // bf16 B-fragment word: word = ((ks*4+nc)*64+lane)*4 + jp (2 shorts/word)
    int rel = (idx < WB_HA) ? idx : idx - WB_HA;
    int jp = rel & 3, lane = (rel >> 2) & 63, rest = rel >> 8;
    int nc = rest & 3, ks = rest >> 2;
    int t0 = ks * 32 + ((lane >> 4) << 3) + jp * 2;
    int h = nc * 16 + (lane & 15);
    float mw0 = sigm(p.mi[h] - p.mi[64 + h]);
    float mw1 = 1.f - mw0;
    float v0, v1;
    if (idx < WB_HA) {
      v0 = hefold(p, t0, h, mw0, mw1);
      v1 = hefold(p, t0 + 1, h, mw0, mw1);
    } else {
      v0 = hafold(p, t0, h, mw0, mw1);
      v1 = hafold(p, t0 + 1, h, mw0, mw1);
    }
    unsigned pk = (unsigned)f2bf(v0) | ((unsigned)f2bf(v1) << 16);
    ws[idx] = __uint_as_float(pk);
  } else if (idx < 38912) {
    int rel = idx - WS_ATT;
    int c = rel >> 8, rem = rel & 255, j = rem >> 2, q = rel & 3;
    int h = c * 4 + q;
    ws[idx] = mo0 * p.heW2[j * 1154 + 1024 + 2 * h] + mo1 * p.heW2[j * 1154 + 1024 + 2 * h + 1];
  } else if (idx < 38976) {
    int j = idx - WS_BATT;
    ws[idx] = mo0 * p.heW2[j * 1154 + 1152] + mo1 * p.heW2[j * 1154 + 1153];
  } else if (idx < 39040) {
    int h = idx - WS_BH;
    ws[idx] = mo0 * p.heb2[1024 + 2 * h] + mo1 * p.heb2[1024 + 2 * h + 1];
  } else if (idx == WS_BC) {
    ws[idx] = mo0 * p.heb2[1152] + mo1 * p.heb2[1153];
  } else if (idx < WS_G1) {
    return;  // LQ region written by block 0
  } else if (idx < WS_G2) {
    int rel = idx - WS_G1;
    int k4 = rel / 1536, r2 = rel % 1536;
    int j = r2 >> 8, lane = (r2 & 255) >> 2, q = rel & 3;
    int row = 4 * k4 + q;
    ws[idx] = (j < 3) ? p.gWih[row * 192 + j * 64 + lane]
                      : p.gWhh[row * 192 + (j - 3) * 64 + lane];
  } else if (idx < WS_E1) {
    int rel = idx - WS_G2;
    int k4 = rel / 1536, r2 = rel % 1536;
    int j = r2 >> 8, lane = (r2 & 255) >> 2, q = rel & 3;
    int row = 4 * k4 + q;
    ws[idx] = (j < 3) ? p.g2Wih[row * 192 + j * 64 + lane]
                      : p.g2Whh[row * 192 + (j - 3) * 64 + lane];
  } else if (idx < WS_E2) {
    int rel = idx - WS_E1;
    int k4 = rel >> 9, j = (rel >> 8) & 1, lane = (rel & 255) >> 2, q = rel & 3;
    int row = 4 * k4 + q;
    ws[idx] = p.eW1[row * 128 + j * 64 + lane];
  } else if (idx < WS_F1) {
    int rel = idx - WS_E2;
    int k4 = rel >> 8, lane = (rel & 255) >> 2, q = rel & 3;
    int row = 4 * k4 + q;
    ws[idx] = p.eW2[row * 64 + lane];
  } else {
    int rel = idx - WS_F1;
    int k4 = rel >> 9, j = (rel >> 8) & 1, lane = (rel & 255) >> 2, q = rel & 3;
    int row = 4 * k4 + q;
    float v;
    if (row < 30) v = (j == 0) ? p.fc1oW[row * 64 + lane] : p.fc1bW[row * 64 + lane];
    else if (row == 30) v = (j == 0) ? p.fc1ob[lane] : p.fc1bb[lane];
    else v = 0.f;
    ws[idx] = v;
  }
}

// ---------------------------------------------------------------------------
// kernel A: hypernet (MFMA contraction) + fc1_own + GRU1 + attack + q_normal.
// The 520x64 contraction per sample used to cost 130 broadcast ds_read_b128 +
// 2080 FMA per sample-pair-matrix (round-6: LDS-pipe + VALU throughput bound,
// ~110us of LDS pipe/CU). Now: T -> bf16 A-fragments in LDS, weights are
// prepacked bf16 B-fragments, 2x(17 ds_read + 68 global + 68 MFMA)/wave.
// D rows m>=4 are garbage and never read.
// ---------------------------------------------------------------------------
__global__ void __launch_bounds__(256, 2) kernelA(Params p, const float* __restrict__ ws,
                                                  float* __restrict__ out) {
  __shared__ float smem[4 * AWAVE];
  const int w = __builtin_amdgcn_readfirstlane((int)(threadIdx.x >> 6));
  const int lane = threadIdx.x & 63;
  float* S = &smem[w * AWAVE];
  unsigned short* ta = (unsigned short*)S;  // 4 rows x TA_SH shorts
  float* SB = S + 1104;                     // sample s at SB + s*ASAMP
  const int i0 = blockIdx.x * 16 + w * 4;

  // zero TA pad rows t=520..543 (persist across both builds)
  if (lane < 24) {
#pragma unroll
    for (int m = 0; m < 4; ++m) ta[m * TA_SH + 520 + lane] = 0;
  }
  // stage ef, af
#pragma unroll
  for (int s = 0; s < 4; ++s) {
    SB[s * ASAMP + 208 + lane] = p.ef[(i0 + s) * 64 + lane];
    if (lane < 56) SB[s * ASAMP + 272 + lane] = p.af[(i0 + s) * 56 + lane];
  }
  // ---- enemy T build -> bf16 TA
  {
    float w1[8];
#pragma unroll
    for (int d = 0; d < 8; ++d) w1[d] = p.heW1[d * 64 + lane];
    const float b1 = p.heb1[lane];
#pragma unroll
    for (int s = 0; s < 4; ++s) {
      float T[8], fs[8];
#pragma unroll
      for (int d = 0; d < 8; ++d) { T[d] = 0.f; fs[d] = 0.f; }
#pragma unroll
      for (int e = 0; e < 8; ++e) {
        float4 a = *(const float4*)&SB[s * ASAMP + 208 + e * 8];
        float4 b = *(const float4*)&SB[s * ASAMP + 208 + e * 8 + 4];
        float acc = b1 + a.x * w1[0] + a.y * w1[1] + a.z * w1[2] + a.w * w1[3] +
                    b.x * w1[4] + b.y * w1[5] + b.z * w1[6] + b.w * w1[7];
        float r = fmaxf(acc, 0.f);
        T[0] += r * a.x; T[1] += r * a.y; T[2] += r * a.z; T[3] += r * a.w;
        T[4] += r * b.x; T[5] += r * b.y; T[6] += r * b.z; T[7] += r * b.w;
        fs[0] += a.x; fs[1] += a.y; fs[2] += a.z; fs[3] += a.w;
        fs[4] += b.x; fs[5] += b.y; fs[6] += b.z; fs[7] += b.w;
      }
#pragma unroll
      for (int d = 0; d < 8; ++d) ta[s * TA_SH + d * 64 + lane] = f2bf(T[d]);
      if (lane == 0) {
#pragma unroll
        for (int d = 0; d < 8; ++d) ta[s * TA_SH + 512 + d] = f2bf(fs[d]);
      }
    }
  }
  // ---- HE MFMA (acc carries into HA)
  f4v acc[4];
#pragma unroll
  for (int nc = 0; nc < 4; ++nc) acc[nc] = (f4v){0.f, 0.f, 0.f, 0.f};
  {
    const s8v* WB = (const s8v*)(ws + WB_HE);
    for (int ks = 0; ks < 17; ++ks) {
      s8v a = *(const s8v*)&ta[(lane & 3) * TA_SH + ks * 32 + ((lane >> 4) << 3)];
#pragma unroll
      for (int nc = 0; nc < 4; ++nc) {
        s8v b = WB[(ks * 4 + nc) * 64 + lane];
        acc[nc] = __builtin_amdgcn_mfma_f32_16x16x32_bf16(a, b, acc[nc], 0, 0, 0);
      }
    }
  }
  // ---- ally T build -> bf16 TA (overwrites t<520; pads persist)
  {
    float w1[8];
#pragma unroll
    for (int d = 0; d < 8; ++d) w1[d] = p.haW1[d * 64 + lane];
    const float b1 = p.hab1[lane];
#pragma unroll
    for (int s = 0; s < 4; ++s) {
      float T[8], fs[8];
#pragma unroll
      for (int d = 0; d < 8; ++d) { T[d] = 0.f; fs[d] = 0.f; }
#pragma unroll
      for (int e = 0; e < 7; ++e) {
        float4 a = *(const float4*)&SB[s * ASAMP + 272 + e * 8];
        float4 b = *(const float4*)&SB[s * ASAMP + 272 + e * 8 + 4];
        float acc2 = b1 + a.x * w1[0] + a.y * w1[1] + a.z * w1[2] + a.w * w1[3] +
                     b.x * w1[4] + b.y * w1[5] + b.z * w1[6] + b.w * w1[7];
        float r = fmaxf(acc2, 0.f);
        T[0] += r * a.x; T[1] += r * a.y; T[2] += r * a.z; T[3] += r * a.w;
        T[4] += r * b.x; T[5] += r * b.y; T[6] += r * b.z; T[7] += r * b.w;
        fs[0] += a.x; fs[1] += a.y; fs[2] += a.z; fs[3] += a.w;
        fs[4] += b.x; fs[5] += b.y; fs[6] += b.z; fs[7] += b.w;
      }
#pragma unroll
      for (int d = 0; d < 8; ++d) ta[s * TA_SH + d * 64 + lane] = f2bf(T[d]);
      if (lane == 0) {
#pragma unroll
        for (int d = 0; d < 8; ++d) ta[s * TA_SH + 512 + d] = f2bf(fs[d]);
      }
    }
  }
  // ---- HA MFMA (continue accumulating)
  {
    const s8v* WB = (const s8v*)(ws + WB_HA);
    for (int ks = 0; ks < 17; ++ks) {
      s8v a = *(const s8v*)&ta[(lane & 3) * TA_SH + ks * 32 + ((lane >> 4) << 3)];
#pragma unroll
      for (int nc = 0; nc < 4; ++nc) {
        s8v b = WB[(ks * 4 + nc) * 64 + lane];
        acc[nc] = __builtin_amdgcn_mfma_f32_16x16x32_bf16(a, b, acc[nc], 0, 0, 0);
      }
    }
  }
  // ---- extract D: sample = reg (rows 0..3 live in lanes 0..15), h = nc*16+lane
  if (lane < 16) {
#pragma unroll
    for (int nc = 0; nc < 4; ++nc) {
#pragma unroll
      for (int r = 0; r < 4; ++r) SB[r * ASAMP + nc * 16 + lane] = acc[nc][r];
    }
  }
  // ---- stage hid and own (own over af)
#pragma unroll
  for (int s = 0; s < 4; ++s) {
    SB[s * ASAMP + 64 + lane] = p.hid[(i0 + s) * 64 + lane];
    if (lane < 32)
      SB[s * ASAMP + 272 + lane] =
          (lane < 30) ? p.own[(i0 + s) * 30 + lane] : (lane == 30 ? 1.f : 0.f);
  }
  // ---- fc1_own + merged -> x at +0 (reads macc from x-slot before overwrite)
  {
    float aO[4] = {0.f, 0.f, 0.f, 0.f};
    const float4* F = (const float4*)(ws + WS_F1);
    for (int k4 = 0; k4 < 8; ++k4) {
      float4 wo = F[k4 * 128 + lane];
#pragma unroll
      for (int s = 0; s < 4; ++s) {
        float4 o4 = *(const float4*)&SB[s * ASAMP + 272 + k4 * 4];
        aO[s] += o4.x * wo.x + o4.y * wo.y + o4.z * wo.z + o4.w * wo.w;
      }
    }
#pragma unroll
    for (int s = 0; s < 4; ++s) {
      const int i = i0 + s;
      float mer = SB[s * ASAMP + lane];
      float x = aO[s] + p.aemb[p.aid[i] * 64 + lane] + p.actemb[p.lid[i] * 64 + lane] + mer;
      SB[s * ASAMP + lane] = fmaxf(x, 0.f);
    }
  }
  // ---- GRU1 (x@0, hid@64) -> hh@128 and out
  {
    const float bi0 = p.gbih[lane] + p.gbhh[lane];
    const float bi1 = p.gbih[64 + lane] + p.gbhh[64 + lane];
    const float bi2i = p.gbih[128 + lane];
    const float bi2h = p.gbhh[128 + lane];
    float A0[4], A1[4], A2[4], B2[4];
#pragma unroll
    for (int s = 0; s < 4; ++s) { A0[s] = bi0; A1[s] = bi1; A2[s] = bi2i; B2[s] = bi2h; }
    const float4* G = (const float4*)(ws + WS_G1);
    for (int k4 = 0; k4 < 16; ++k4) {
      float4 w0 = G[k4 * 384 + lane];
      float4 w1v = G[k4 * 384 + 64 + lane];
      float4 w2v = G[k4 * 384 + 128 + lane];
      float4 w3 = G[k4 * 384 + 192 + lane];
      float4 w4v = G[k4 * 384 + 256 + lane];
      float4 w5 = G[k4 * 384 + 320 + lane];
#pragma unroll
      for (int s = 0; s < 4; ++s) {
        float4 x4 = *(const float4*)&SB[s * ASAMP + k4 * 4];
        float4 h4 = *(const float4*)&SB[s * ASAMP + 64 + k4 * 4];
        A0[s] += x4.x * w0.x + x4.y * w0.y + x4.z * w0.z + x4.w * w0.w +
                 h4.x * w3.x + h4.y * w3.y + h4.z * w3.z + h4.w * w3.w;
        A1[s] += x4.x * w1v.x + x4.y * w1v.y + x4.z * w1v.z + x4.w * w1v.w +
                 h4.x * w4v.x + h4.y * w4v.y + h4.z * w4v.z + h4.w * w4v.w;
        A2[s] += x4.x * w2v.x + x4.y * w2v.y + x4.z * w2v.z + x4.w * w2v.w;
        B2[s] += h4.x * w5.x + h4.y * w5.y + h4.z * w5.z + h4.w * w5.w;
      }
    }
#pragma unroll
    for (int s = 0; s < 4; ++s) {
      float r = sigm(A0[s]);
      float z = sigm(A1[s]);
      float n = tanh_(A2[s] + r * B2[s]);
      float hp = SB[s * ASAMP + 64 + lane];
      float hh = (1.f - z) * n + z * hp;
      SB[s * ASAMP + 128 + lane] = hh;
      out[HH_OFF + (i0 + s) * 64 + lane] = hh;
    }
  }
  // ---- attack head -> qbuf@192+6..13
  {
    float v4[4];
    const float batt = ws[WS_BATT + lane];
#pragma unroll
    for (int s = 0; s < 4; ++s) v4[s] = batt;
    const float4* A4 = (const float4*)(ws + WS_ATT);
    for (int c = 0; c < 16; ++c) {
      float4 wv = A4[c * 64 + lane];
#pragma unroll
      for (int s = 0; s < 4; ++s) {
        float4 h4 = *(const float4*)&SB[s * ASAMP + 128 + c * 4];
        v4[s] += h4.x * wv.x + h4.y * wv.y + h4.z * wv.z + h4.w * wv.w;
      }
    }
    float w1[8];
#pragma unroll
    for (int d = 0; d < 8; ++d) w1[d] = p.heW1[d * 64 + lane];
    const float b1 = p.heb1[lane];
    const float bhv = ws[WS_BH + lane];
    const float bc = ws[WS_BC];
#pragma unroll
    for (int s = 0; s < 4; ++s) {
      float red[9];
#pragma unroll
      for (int e = 0; e < 8; ++e) {
        float4 a = *(const float4*)&SB[s * ASAMP + 208 + e * 8];
        float4 b = *(const float4*)&SB[s * ASAMP + 208 + e * 8 + 4];
        float acc2 = b1 + a.x * w1[0] + a.y * w1[1] + a.z * w1[2] + a.w * w1[3] +
                     b.x * w1[4] + b.y * w1[5] + b.z * w1[6] + b.w * w1[7];
        red[e] = fmaxf(acc2, 0.f) * v4[s];
      }
      red[8] = SB[s * ASAMP + 128 + lane] * bhv;
#pragma unroll
      for (int off = 32; off >= 1; off >>= 1) {
#pragma unroll
        for (int t = 0; t < 9; ++t) red[t] += __shfl_xor(red[t], off, 64);
      }
      if (lane == 0) {
#pragma unroll
        for (int e = 0; e < 8; ++e) SB[s * ASAMP + 192 + 6 + e] = red[e] + red[8] + bc;
      }
    }
  }
  // ---- q_normal + partial assembly: out[q] = qo + lq ; out[LQE] = lq
  if (lane < 56) {
    const int s = lane / 14, c = lane % 14;
    const int i = i0 + s;
    float qo;
    if (c < 6) {
      float a2 = p.fc2nb[c];
      for (int h = 0; h < 64; ++h) a2 += SB[s * ASAMP + 128 + h] * p.fc2nW[h * 6 + c];
      qo = a2;
    } else {
      qo = SB[s * ASAMP + 192 + c];
    }
    float lq = ws[WS_LQ + (i & 7) * 14 + c];
    out[i * 14 + c] = qo + lq;
    out[LQE_OFF + i * 14 + c] = lq;
  }
}

// ---------------------------------------------------------------------------
// kernel B: fc1b + GRU2 + enc + fc3. Writes out[QF], adds qf into out[q].
// ---------------------------------------------------------------------------
__global__ void __launch_bounds__(256, 2) kernelB(Params p, const float* __restrict__ ws,
                                                  float* __restrict__ out) {
  __shared__ float smem[4 * 4 * BSTR];
  const int w = __builtin_amdgcn_readfirstlane((int)(threadIdx.x >> 6));
  const int lane = threadIdx.x & 63;
  float* S = &smem[w * 4 * BSTR];
  const int i0 = blockIdx.x * 16 + w * 4;

#pragma unroll
  for (int s = 0; s < 4; ++s) {
    S[s * BSTR + 64 + lane] = p.hid[(i0 + s) * 64 + lane];
    if (lane < 32)
      S[s * BSTR + 192 + lane] =
          (lane < 30) ? p.own[(i0 + s) * 30 + lane] : (lane == 30 ? 1.f : 0.f);
  }
  {
    float aB[4] = {0.f, 0.f, 0.f, 0.f};
    const float4* F = (const float4*)(ws + WS_F1);
    for (int k4 = 0; k4 < 8; ++k4) {
      float4 wb = F[k4 * 128 + 64 + lane];
#pragma unroll
      for (int s = 0; s < 4; ++s) {
        float4 o4 = *(const float4*)&S[s * BSTR + 192 + k4 * 4];
        aB[s] += o4.x * wb.x + o4.y * wb.y + o4.z * wb.z + o4.w * wb.w;
      }
    }
#pragma unroll
    for (int s = 0; s < 4; ++s) S[s * BSTR + lane] = fmaxf(aB[s], 0.f);
  }
  {
    const float bi0 = p.g2bih[lane] + p.g2bhh[lane];
    const float bi1 = p.g2bih[64 + lane] + p.g2bhh[64 + lane];
    const float bi2i = p.g2bih[128 + lane];
    const float bi2h = p.g2bhh[128 + lane];
    float A0[4], A1[4], A2[4], B2[4];
#pragma unroll
    for (int s = 0; s < 4; ++s) { A0[s] = bi0; A1[s] = bi1; A2[s] = bi2i; B2[s] = bi2h; }
    const float4* G = (const float4*)(ws + WS_G2);
    for (int k4 = 0; k4 < 16; ++k4) {
      float4 w0 = G[k4 * 384 + lane];
      float4 w1v = G[k4 * 384 + 64 + lane];
      float4 w2v = G[k4 * 384 + 128 + lane];
      float4 w3 = G[k4 * 384 + 192 + lane];
      float4 w4v = G[k4 * 384 + 256 + lane];
      float4 w5 = G[k4 * 384 + 320 + lane];
#pragma unroll
      for (int s = 0; s < 4; ++s) {
        float4 x4 = *(const float4*)&S[s * BSTR + k4 * 4];
        float4 h4 = *(const float4*)&S[s * BSTR + 64 + k4 * 4];
        A0[s] += x4.x * w0.x + x4.y * w0.y + x4.z * w0.z + x4.w * w0.w +
                 h4.x * w3.x + h4.y * w3.y + h4.z * w3.z + h4.w * w3.w;
        A1[s] += x4.x * w1v.x + x4.y * w1v.y + x4.z * w1v.z + x4.w * w1v.w +
                 h4.x * w4v.x + h4.y * w4v.y + h4.z * w4v.z + h4.w * w4v.w;
        A2[s] += x4.x * w2v.x + x4.y * w2v.y + x4.z * w2v.z + x4.w * w2v.w;
        B2[s] += h4.x * w5.x + h4.y * w5.y + h4.z * w5.z + h4.w * w5.w;
      }
    }
#pragma unroll
    for (int s = 0; s < 4; ++s) {
      float r = sigm(A0[s]);
      float z = sigm(A1[s]);
      float n = tanh_(A2[s] + r * B2[s]);
      float hp = S[s * BSTR + 64 + lane];
      S[s * BSTR + 128 + lane] = (1.f - z) * n + z * hp;
    }
  }
  {
    float C0[4], C1[4];
#pragma unroll
    for (int s = 0; s < 4; ++s) { C0[s] = p.eb1[lane]; C1[s] = p.eb1[64 + lane]; }
    const float4* E1 = (const float4*)(ws + WS_E1);
    for (int k4 = 0; k4 < 16; ++k4) {
      float4 w0 = E1[k4 * 128 + lane];
      float4 w1v = E1[k4 * 128 + 64 + lane];
#pragma unroll
      for (int s = 0; s < 4; ++s) {
        float4 g4 = *(const float4*)&S[s * BSTR + 128 + k4 * 4];
        C0[s] += g4.x * w0.x + g4.y * w0.y + g4.z * w0.z + g4.w * w0.w;
        C1[s] += g4.x * w1v.x + g4.y * w1v.y + g4.z * w1v.z + g4.w * w1v.w;
      }
    }
#pragma unroll
    for (int s = 0; s < 4; ++s) {
      S[s * BSTR + 192 + lane] = fmaxf(C0[s], 0.f);
      S[s * BSTR + 256 + lane] = fmaxf(C1[s], 0.f);
    }
  }
  {
    float Z[4];
#pragma unroll
    for (int s = 0; s < 4; ++s) Z[s] = p.eb2[lane];
    const float4* E2 = (const float4*)(ws + WS_E2);
    for (int k4 = 0; k4 < 32; ++k4) {
      float4 wv = E2[k4 * 64 + lane];
#pragma unroll
      for (int s = 0; s < 4; ++s) {
        float4 z4 = *(const float4*)&S[s * BSTR + 192 + k4 * 4];
        Z[s] += z4.x * wv.x + z4.y * wv.y + z4.z * wv.z + z4.w * wv.w;
      }
    }
#pragma unroll
    for (int s = 0; s < 4; ++s) S[s * BSTR + 320 + lane] = Z[s];
  }
  if (lane < 56) {
    const int s = lane / 14, c = lane % 14;
    const int i = i0 + s;
    float qf = p.fc3b[c];
    for (int k = 0; k < 64; ++k) qf += S[s * BSTR + 320 + k] * p.fc3W[k * 14 + c];
    out[QF_OFF + i * 14 + c] = qf;
    out[i * 14 + c] += qf;
  }
}

extern "C" void kernel_launch(void* const* d_in, const int* in_sizes, int n_in,
                              void* d_out, int out_size, void* d_ws, size_t ws_size,
                              hipStream_t stream) {
  (void)in_sizes; (void)n_in; (void)out_size; (void)ws_size;
  Params p;
  p.own = (const float*)d_in[1];
  p.ef = (const float*)d_in[2];
  p.af = (const float*)d_in[3];
  p.aid = (const int*)d_in[4];
  p.lid = (const int*)d_in[5];
  p.hid = (const float*)d_in[6];
  p.fc1oW = (const float*)d_in[7];
  p.fc1ob = (const float*)d_in[8];
  p.aemb = (const float*)d_in[9];
  p.actemb = (const float*)d_in[10];
  p.heW1 = (const float*)d_in[11];
  p.heb1 = (const float*)d_in[12];
  p.heW2 = (const float*)d_in[13];
  p.heb2 = (const float*)d_in[14];
  p.haW1 = (const float*)d_in[15];
  p.hab1 = (const float*)d_in[16];
  p.haW2 = (const float*)d_in[17];
  p.hab2 = (const float*)d_in[18];
  p.mi = (const float*)d_in[19];
  p.mo = (const float*)d_in[20];
  p.gWih = (const float*)d_in[21];
  p.gWhh = (const float*)d_in[22];
  p.gbih = (const float*)d_in[23];
  p.gbhh = (const float*)d_in[24];
  p.fc2nW = (const float*)d_in[25];
  p.fc2nb = (const float*)d_in[26];
  p.fc1bW = (const float*)d_in[27];
  p.fc1bb = (const float*)d_in[28];
  p.g2Wih = (const float*)d_in[29];
  p.g2Whh = (const float*)d_in[30];
  p.g2bih = (const float*)d_in[31];
  p.g2bhh = (const float*)d_in[32];
  p.eW1 = (const float*)d_in[33];
  p.eb1 = (const float*)d_in[34];
  p.eW2 = (const float*)d_in[35];
  p.eb2 = (const float*)d_in[36];
  p.fc3W = (const float*)d_in[37];
  p.fc3b = (const float*)d_in[38];
  p.mlpW = (const float*)d_in[39];
  p.mlpb = (const float*)d_in[40];
  float* ws = (float*)d_ws;
  float* out = (float*)d_out;
  prep_kernel<<<dim3(214), dim3(512), 0, stream>>>(p, ws);
  kernelA<<<dim3(1024), dim3(256), 0, stream>>>(p, ws, out);
  kernelB<<<dim3(1024), dim3(256), 0, stream>>>(p, ws, out);
}